// Round 2
// baseline (1611.087 us; speedup 1.0000x reference)
//
#include <hip/hip_runtime.h>

// Problem constants: B=512, T=128, I=128, H=512
#define TI 16384   // T*I
#define HD 512
#define KD 640     // I+H
#define G4 2048    // 4*H

typedef short short8 __attribute__((ext_vector_type(8)));
typedef __bf16 bf16x8 __attribute__((ext_vector_type(8)));
typedef float floatx4 __attribute__((ext_vector_type(4)));

static __device__ __forceinline__ unsigned short f2bf(float f) {
  unsigned int u = __float_as_uint(f);
  u += 0x7fffu + ((u >> 16) & 1u);   // RNE
  return (unsigned short)(u >> 16);
}
static __device__ __forceinline__ float sigmoidf_(float x) {
  return 1.f / (1.f + __expf(-x));
}
static __device__ __forceinline__ float tanhf_(float x) {
  float ax = fabsf(x);
  float e = __expf(-2.f * ax);
  float r = 1.f - 2.f * e / (1.f + e);
  return copysignf(r, x);
}

// ---------------- transpose + cast: src[R][C] fp32 -> dst[C][R] bf16
__global__ __launch_bounds__(256) void transpose_f32_bf16(
    const float* __restrict__ src, unsigned short* __restrict__ dst,
    int R, int C) {
  __shared__ unsigned short tile[64][80];  // 160B row stride: 16B aligned
  int nR = R >> 6;
  int tr = blockIdx.x % nR;
  int tc = blockIdx.x / nR;
  int tid = threadIdx.x;
#pragma unroll
  for (int i = 0; i < 2; ++i) {
    int seg = tid + i * 256;
    int row = seg >> 3, ks8 = (seg & 7) * 8;
    const float* p = src + (size_t)(tr * 64 + row) * C + tc * 64 + ks8;
    short8 v;
#pragma unroll
    for (int q = 0; q < 8; ++q) v[q] = (short)f2bf(p[q]);
    *(short8*)(&tile[row][ks8]) = v;
  }
  __syncthreads();
#pragma unroll
  for (int i = 0; i < 2; ++i) {
    int seg = tid + i * 256;
    int cl = seg >> 3, rs8 = (seg & 7) * 8;
    short8 v;
#pragma unroll
    for (int q = 0; q < 8; ++q) v[q] = (short)tile[rs8 + q][cl];
    *(short8*)(dst + (size_t)(tc * 64 + cl) * R + tr * 64 + rs8) = v;
  }
}

// ---------------- one LSTM timestep for BOTH cells
// grid: 256 blocks = lstm(2) x mb(8) x nb(16); tile M=64 x N=128 (32 h x 4 gates)
// wave layout: 2x2 -> each wave: rows [wm*32,+32), cols = 4 gates x 16 h
__global__ __launch_bounds__(256) void lstm_step(
    const float* __restrict__ xs, const float* __restrict__ xl,
    const unsigned short* __restrict__ WTs, const unsigned short* __restrict__ WTl,
    const float* __restrict__ bs, const float* __restrict__ bl,
    const unsigned short* __restrict__ hs_r, unsigned short* __restrict__ hs_w,
    const unsigned short* __restrict__ hl_r, unsigned short* __restrict__ hl_w,
    float* __restrict__ cs, float* __restrict__ cl_, int t) {
  const int bx = blockIdx.x;
  const int lstm = bx & 1;
  const int mb = (bx >> 1) & 7;
  const int nb = bx >> 4;

  const float* x = lstm ? xl : xs;
  const unsigned short* WT = lstm ? WTl : WTs;
  const float* bias = lstm ? bl : bs;
  const unsigned short* hr = lstm ? hl_r : hs_r;
  unsigned short* hw = lstm ? hl_w : hs_w;
  float* cbuf = lstm ? cl_ : cs;

  __shared__ unsigned short As[64][88];   // pad->176B stride: aligned, 2-way banks
  __shared__ unsigned short Bs[128][88];

  const int tid = threadIdx.x;
  const int wave = tid >> 6;
  const int lane = tid & 63;
  const int quad = lane >> 4;
  const int lrow = lane & 15;
  const int wm = wave & 1;
  const int wn = wave >> 1;

  floatx4 acc[8];
#pragma unroll
  for (int i = 0; i < 8; ++i) acc[i] = (floatx4){0.f, 0.f, 0.f, 0.f};

  for (int k0 = 0; k0 < KD; k0 += 64) {
    // stage A tile (64 rows x 64 k): k<128 from x_t (fp32->bf16), else h_{t-1} (bf16)
#pragma unroll
    for (int i = 0; i < 2; ++i) {
      int seg = tid + i * 256;
      int row = seg >> 3;
      int ks8 = (seg & 7) * 8;
      int kg = k0 + ks8;
      int b = mb * 64 + row;
      short8 v;
      if (kg < 128) {
        const float* p = x + (size_t)b * TI + t * 128 + kg;
#pragma unroll
        for (int q = 0; q < 8; ++q) v[q] = (short)f2bf(p[q]);
      } else if (t > 0) {
        v = *(const short8*)(hr + (size_t)b * HD + (kg - 128));
      } else {
        v = (short8){0, 0, 0, 0, 0, 0, 0, 0};
      }
      *(short8*)(&As[row][ks8]) = v;
    }
    // stage B^T tile (128 n x 64 k); n_local -> (hchunk, gate, col)
#pragma unroll
    for (int i = 0; i < 4; ++i) {
      int seg = tid + i * 256;
      int n = seg >> 3;
      int ks8 = (seg & 7) * 8;
      int hc = n >> 6, g = (n >> 4) & 3, c16 = n & 15;
      int wrow = g * HD + nb * 32 + hc * 16 + c16;
      *(short8*)(&Bs[n][ks8]) =
          *(const short8*)(WT + (size_t)wrow * KD + k0 + ks8);
    }
    __syncthreads();
#pragma unroll
    for (int ks = 0; ks < 64; ks += 32) {
      int kq = ks + quad * 8;
      bf16x8 a0 = __builtin_bit_cast(bf16x8, *(const short8*)(&As[wm * 32 + lrow][kq]));
      bf16x8 a1 = __builtin_bit_cast(bf16x8, *(const short8*)(&As[wm * 32 + 16 + lrow][kq]));
#pragma unroll
      for (int g = 0; g < 4; ++g) {
        bf16x8 bfr = __builtin_bit_cast(bf16x8, *(const short8*)(&Bs[wn * 64 + g * 16 + lrow][kq]));
        acc[g] = __builtin_amdgcn_mfma_f32_16x16x32_bf16(a0, bfr, acc[g], 0, 0, 0);
        acc[4 + g] = __builtin_amdgcn_mfma_f32_16x16x32_bf16(a1, bfr, acc[4 + g], 0, 0, 0);
      }
    }
    __syncthreads();
  }

  // epilogue: gate math, lane-local (all 4 gates in this wave's acc tiles)
  const int hidx = nb * 32 + wn * 16 + lrow;
  const float bf = bias[0 * HD + hidx];
  const float bi = bias[1 * HD + hidx];
  const float bo = bias[2 * HD + hidx];
  const float bc = bias[3 * HD + hidx];
#pragma unroll
  for (int mt = 0; mt < 2; ++mt) {
#pragma unroll
    for (int r = 0; r < 4; ++r) {
      int b = mb * 64 + wm * 32 + mt * 16 + quad * 4 + r;
      float fg = acc[mt * 4 + 0][r] + bf;
      float ig = acc[mt * 4 + 1][r] + bi;
      float og = acc[mt * 4 + 2][r] + bo;
      float cg = acc[mt * 4 + 3][r] + bc;
      float cold = (t > 0) ? cbuf[(size_t)b * HD + hidx] : 0.f;
      float cn = sigmoidf_(fg) * cold + sigmoidf_(ig) * tanhf_(cg);
      float hn = sigmoidf_(og) * tanhf_(cn);
      cbuf[(size_t)b * HD + hidx] = cn;
      hw[(size_t)b * HD + hidx] = f2bf(hn);
    }
  }
}

// ---------------- out = tanh(concat(hs,hl) @ out_W + out_b), fp32 out
// grid 32 = mb(8) x nb(4); tile 64 x 128, K=1024
__global__ __launch_bounds__(256) void out_gemm(
    const unsigned short* __restrict__ hs, const unsigned short* __restrict__ hl,
    const unsigned short* __restrict__ WTo,  // [512][1024] bf16
    const float* __restrict__ ob, float* __restrict__ out) {
  const int bx = blockIdx.x;
  const int mb = bx & 7;
  const int nb = bx >> 3;

  __shared__ unsigned short As[64][88];
  __shared__ unsigned short Bs[128][88];

  const int tid = threadIdx.x;
  const int wave = tid >> 6;
  const int lane = tid & 63;
  const int quad = lane >> 4;
  const int lrow = lane & 15;
  const int wm = wave & 1;
  const int wn = wave >> 1;

  floatx4 acc[8];
#pragma unroll
  for (int i = 0; i < 8; ++i) acc[i] = (floatx4){0.f, 0.f, 0.f, 0.f};

  for (int k0 = 0; k0 < 1024; k0 += 64) {
#pragma unroll
    for (int i = 0; i < 2; ++i) {
      int seg = tid + i * 256;
      int row = seg >> 3;
      int ks8 = (seg & 7) * 8;
      int kg = k0 + ks8;
      int b = mb * 64 + row;
      const unsigned short* src =
          (kg < 512) ? (hs + (size_t)b * HD + kg) : (hl + (size_t)b * HD + (kg - 512));
      *(short8*)(&As[row][ks8]) = *(const short8*)src;
    }
#pragma unroll
    for (int i = 0; i < 4; ++i) {
      int seg = tid + i * 256;
      int n = seg >> 3;
      int ks8 = (seg & 7) * 8;
      *(short8*)(&Bs[n][ks8]) =
          *(const short8*)(WTo + (size_t)(nb * 128 + n) * 1024 + k0 + ks8);
    }
    __syncthreads();
#pragma unroll
    for (int ks = 0; ks < 64; ks += 32) {
      int kq = ks + quad * 8;
      bf16x8 a0 = __builtin_bit_cast(bf16x8, *(const short8*)(&As[wm * 32 + lrow][kq]));
      bf16x8 a1 = __builtin_bit_cast(bf16x8, *(const short8*)(&As[wm * 32 + 16 + lrow][kq]));
#pragma unroll
      for (int nt = 0; nt < 4; ++nt) {
        bf16x8 bfr = __builtin_bit_cast(bf16x8, *(const short8*)(&Bs[wn * 64 + nt * 16 + lrow][kq]));
        acc[nt] = __builtin_amdgcn_mfma_f32_16x16x32_bf16(a0, bfr, acc[nt], 0, 0, 0);
        acc[4 + nt] = __builtin_amdgcn_mfma_f32_16x16x32_bf16(a1, bfr, acc[4 + nt], 0, 0, 0);
      }
    }
    __syncthreads();
  }
#pragma unroll
  for (int mt = 0; mt < 2; ++mt) {
#pragma unroll
    for (int nt = 0; nt < 4; ++nt) {
      int n = nb * 128 + wn * 64 + nt * 16 + lrow;
      float bv = ob[n];
#pragma unroll
      for (int r = 0; r < 4; ++r) {
        int b = mb * 64 + wm * 32 + mt * 16 + quad * 4 + r;
        out[(size_t)b * HD + n] = tanhf_(acc[mt * 4 + nt][r] + bv);
      }
    }
  }
}

extern "C" void kernel_launch(void* const* d_in, const int* in_sizes, int n_in,
                              void* d_out, int out_size, void* d_ws, size_t ws_size,
                              hipStream_t stream) {
  (void)in_sizes; (void)n_in; (void)out_size; (void)ws_size;
  const float* xs = (const float*)d_in[0];  // s_inputs [512][128][128] f32
  const float* xl = (const float*)d_in[1];  // l_inputs
  // d_in[2]=dow, d_in[3]=hour: unused by reference
  const float* sW = (const float*)d_in[4];  // [640][2048] f32
  const float* sb = (const float*)d_in[5];  // [2048] f32
  const float* lW = (const float*)d_in[6];
  const float* lb = (const float*)d_in[7];
  const float* oW = (const float*)d_in[8];  // [1024][512] f32
  const float* ob = (const float*)d_in[9];  // [512] f32

  unsigned short* WTs = (unsigned short*)d_ws;            // [2048][640] bf16
  unsigned short* WTl = WTs + (size_t)G4 * KD;            // [2048][640] bf16
  unsigned short* WTo = WTl + (size_t)G4 * KD;            // [512][1024] bf16
  unsigned short* hs0 = WTo + (size_t)HD * 1024;
  unsigned short* hs1 = hs0 + (size_t)512 * HD;
  unsigned short* hl0 = hs1 + (size_t)512 * HD;
  unsigned short* hl1 = hl0 + (size_t)512 * HD;
  float* cs = (float*)(hl1 + (size_t)512 * HD);
  float* cl = cs + (size_t)512 * HD;

  transpose_f32_bf16<<<(640 / 64) * (2048 / 64), 256, 0, stream>>>(sW, WTs, 640, 2048);
  transpose_f32_bf16<<<(640 / 64) * (2048 / 64), 256, 0, stream>>>(lW, WTl, 640, 2048);
  transpose_f32_bf16<<<(1024 / 64) * (512 / 64), 256, 0, stream>>>(oW, WTo, 1024, 512);

  for (int t = 0; t < 128; ++t) {
    unsigned short* hsr = (t & 1) ? hs1 : hs0;
    unsigned short* hsw = (t & 1) ? hs0 : hs1;
    unsigned short* hlr = (t & 1) ? hl1 : hl0;
    unsigned short* hlw = (t & 1) ? hl0 : hl1;
    lstm_step<<<256, 256, 0, stream>>>(xs, xl, WTs, WTl, sb, lb,
                                       hsr, hsw, hlr, hlw, cs, cl, t);
  }
  // t=127 (odd) wrote hs0/hl0
  out_gemm<<<32, 256, 0, stream>>>(hs0, hl0, WTo, ob, (float*)d_out);
}